// Round 4
// baseline (1495.594 us; speedup 1.0000x reference)
//
#include <hip/hip_runtime.h>
#include <hip/hip_bf16.h>
#include <stdint.h>

#define Bn 256
#define Tn 127
#define Kn 128
#define Hn 256

typedef float f32x4 __attribute__((ext_vector_type(4)));
typedef short s16x8 __attribute__((ext_vector_type(8)));
typedef unsigned int u32x4 __attribute__((ext_vector_type(4)));

// ws layout
#define GX_BYTES    66584576ULL  // bf16 [32][127][2][8][4][128]
#define RECL2_OFF   66584576ULL  // u64 [32 g][2 s][2 parity][512 tid][2] (L2-path)
#define REC_BYTES   1048576ULL
#define RECIC_OFF   (RECL2_OFF + REC_BYTES)   // IC-path backstop (if ws allows)

__device__ __forceinline__ float bf2f(unsigned short b){
  union { unsigned u; float f; } v; v.u = ((unsigned)b) << 16; return v.f;
}
__device__ __forceinline__ unsigned short f2bf_rn(float f){
  union { __hip_bfloat16 h; unsigned short s; } u;
  u.h = __float2bfloat16(f);
  return u.s;
}
__device__ __forceinline__ s16x8 cvt8(f32x4 a, f32x4 b){
  union { __hip_bfloat162 h2; unsigned short s[2]; } u0,u1,u2,u3;
  u0.h2 = __float22bfloat162_rn(float2{a[0],a[1]});
  u1.h2 = __float22bfloat162_rn(float2{a[2],a[3]});
  u2.h2 = __float22bfloat162_rn(float2{b[0],b[1]});
  u3.h2 = __float22bfloat162_rn(float2{b[2],b[3]});
  s16x8 r;
  r[0]=(short)u0.s[0]; r[1]=(short)u0.s[1]; r[2]=(short)u1.s[0]; r[3]=(short)u1.s[1];
  r[4]=(short)u2.s[0]; r[5]=(short)u2.s[1]; r[6]=(short)u3.s[0]; r[7]=(short)u3.s[1];
  return r;
}
__device__ __forceinline__ float sigf(float x){ return 1.f/(1.f+__expf(-x)); }
__device__ __forceinline__ float tanh_fast(float x){
  float ax = fabsf(x);
  float e = __expf(-2.f*ax);
  float t = (1.f - e)/(1.f + e);
  return x < 0.f ? -t : t;
}

// L2-visible 16B load (bypass L1 only -> hits the XCD-shared L2)
__device__ __forceinline__ u32x4 ld_b128_sc0(const void* p){
  u32x4 r;
  asm volatile("global_load_dwordx4 %0, %1, off sc0\n\ts_waitcnt vmcnt(0)"
               : "=v"(r) : "v"(p) : "memory");
  return r;
}
// plain 16B store (lands in producer's XCD L2, visible XCD-wide)
__device__ __forceinline__ void st_b128_l2(void* p, u32x4 v){
  asm volatile("global_store_dwordx4 %0, %1, off" :: "v"(p), "v"(v) : "memory");
}

// ---------------- Phase 0: alpha = softmax(x_score), weight = alpha*input -----
__global__ __launch_bounds__(256) void phase0_kernel(
    const float* __restrict__ in, const float* __restrict__ fc_w,
    float* __restrict__ out)
{
  const int b    = blockIdx.x;
  const int tid  = threadIdx.x;
  const int k    = tid & 127;
  const int half = tid >> 7;
  __shared__ float wx[Tn+1];
  __shared__ float partial[2][128];
  __shared__ float red[8];
  __shared__ float alpha_s[128];
  if (tid < Tn) wx[tid] = fc_w[2*Hn + tid];
  __syncthreads();

  const float* ib = in + (size_t)b*Tn*Kn;
  const int t0 = half*64, t1 = half ? Tn : 64;
  float acc = 0.f;
  for (int t=t0; t<t1; t++) acc += ib[t*Kn + k] * wx[t];
  partial[half][k] = acc;
  __syncthreads();
  const float tot = partial[0][k] + partial[1][k];

  float mx = tot;
#pragma unroll
  for (int o=32;o>0;o>>=1) mx = fmaxf(mx, __shfl_xor(mx, o));
  const int wv = tid >> 6;
  if ((tid & 63) == 0) red[wv] = mx;
  __syncthreads();
  mx = fmaxf(fmaxf(red[0],red[1]), fmaxf(red[2],red[3]));
  float e = __expf(tot - mx);
  float sm = e;
#pragma unroll
  for (int o=32;o>0;o>>=1) sm += __shfl_xor(sm, o);
  if ((tid & 63) == 0) red[4+wv] = sm;
  __syncthreads();
  if (half == 0) alpha_s[k] = e / (red[4] + red[5]);
  __syncthreads();

  const int k4 = tid & 31;
  const int tr = tid >> 5;
  const f32x4 al4 = *(const f32x4*)&alpha_s[k4*4];
  float* ob = out + (size_t)b*Tn*Kn;
  for (int t=tr; t<Tn; t+=8){
    f32x4 v = *(const f32x4*)(ib + t*Kn + k4*4);
    v[0]*=al4[0]; v[1]*=al4[1]; v[2]*=al4[2]; v[3]*=al4[3];
    *(f32x4*)(ob + t*Kn + k4*4) = v;
  }
}

// ---------------- Phase GX: gx = x @ W_ih^T + bias, packed in MFMA C-layout --
// Grid 512 = 32 groups x 16 tp-blocks; each block handles 4 t-pairs (W_ih
// read+convert amortized 4x).
__global__ __launch_bounds__(256) void gx_kernel(
    const float* __restrict__ xw, const float* __restrict__ W_ih,
    const float* __restrict__ b_ih, const float* __restrict__ b_hh,
    __hip_bfloat16* __restrict__ gx)
{
  const int g    = blockIdx.x & 31;
  const int tpb  = blockIdx.x >> 5;       // 0..15
  const int tid  = threadIdx.x;
  const int wv   = tid >> 6;
  const int lane = tid & 63;
  const int c    = lane & 15;
  const int quad = lane >> 4;

  const int b  = g*8 + (c & 7);

  s16x8 afr[4][4];
#pragma unroll
  for (int tpi=0; tpi<4; tpi++){
    const int t0 = (tpb*4 + tpi)*2;
    const int tt = min(t0 + (c >> 3), Tn-1);
    const float* xp = xw + ((size_t)b*Tn + tt)*Kn + quad*8;
#pragma unroll
    for (int kb=0; kb<4; kb++)
      afr[tpi][kb] = cvt8(*(const f32x4*)(xp + kb*32), *(const f32x4*)(xp + kb*32 + 4));
  }

  const int tof = (quad >> 1);
  const int mh  = (quad & 1) * 4;

  for (int j = wv*16; j < wv*16+16; j++){
    const int n = j*16 + c;
    const float bias = b_ih[n] + b_hh[n];
    const float* wp = W_ih + (size_t)n*Kn + quad*8;
    s16x8 bfr[4];
#pragma unroll
    for (int kb=0; kb<4; kb++)
      bfr[kb] = cvt8(*(const f32x4*)(wp + kb*32), *(const f32x4*)(wp + kb*32 + 4));
    const int G = j >> 4, rem = j & 15, s = rem >> 3, w8 = rem & 7;
#pragma unroll
    for (int tpi=0; tpi<4; tpi++){
      f32x4 acc = {bias, bias, bias, bias};
#pragma unroll
      for (int kb=0; kb<4; kb++)
        acc = __builtin_amdgcn_mfma_f32_16x16x32_bf16(afr[tpi][kb], bfr[kb], acc, 0,0,0);
      const int trow = (tpb*4 + tpi)*2 + tof;
      if (trow < Tn){
        __hip_bfloat16* dst = gx +
          (((((size_t)g*Tn + trow)*2 + s)*8 + w8)*4 + G)*128 + c*8 + mh;
        ushort4 pk;
        pk.x = f2bf_rn(acc[0]); pk.y = f2bf_rn(acc[1]);
        pk.z = f2bf_rn(acc[2]); pk.w = f2bf_rn(acc[3]);
        *(ushort4*)dst = pk;
      }
    }
  }
}

// ---------------- Scan: 32 groups x 2 N-slices, W_hh-only in registers ------
// Pair (bid, bid^8) shares an XCD under the bid%8 round-robin mapping, so the
// h-exchange goes through the SHARED XCD L2: producer dual-publishes the
// tagged record (plain dwordx4 store -> L2; 2x u64 agent atomics -> IC
// backstop); consumer spin-polls the L2 copy with sc0 loads and falls back to
// the IC copy on timeout (correct under ANY block->XCD mapping; never hangs).
__global__ __launch_bounds__(512, 2) void scan_kernel(
    const float* __restrict__ W_hh, float* __restrict__ out,
    const __hip_bfloat16* __restrict__ gx,
    unsigned long long* __restrict__ recL2, unsigned long long* __restrict__ recIC)
{
  const int bid  = blockIdx.x;
  const int s    = (bid >> 3) & 1;                  // slice
  const int g    = (bid & 7) | ((bid >> 4) << 3);   // group; pair = bid ^ 8
  const int b0   = g * 8;
  const int tid  = threadIdx.x;
  const int w    = tid >> 6;          // wave 0..7 (unit-group)
  const int lane = tid & 63;
  const int c    = lane & 15;
  const int quad = lane >> 4;
  const int u    = s*128 + w*16 + c;  // global hidden unit

  __shared__ __align__(16) unsigned short hhi[2*8*272];
  __shared__ __align__(16) unsigned short hlo[2*8*272];

  // persistent W_hh B-frags: 4 gates x 8 kb = 128 regs
  s16x8 whh[4][8];
#pragma unroll
  for (int G=0; G<4; G++){
    const float* p0 = W_hh + (size_t)(G*Hn + u)*Hn + quad*8;
#pragma unroll
    for (int kb=0; kb<8; kb++)
      whh[G][kb] = cvt8(*(const f32x4*)(p0 + kb*32), *(const f32x4*)(p0 + kb*32 + 4));
  }

  const int rsel0 = (quad >> 1) * 2;
  const int prr0  = rsel0 ^ 2;
  const int m0    = (quad & 1)*4 + rsel0;
  float cst[2] = {0.f, 0.f};

  const size_t enc_base = (size_t)Bn*Tn*Kn;
  unsigned long long* recL2_mine  = recL2 + ((size_t)g*2 + s)*2048;
  unsigned long long* recL2_other = recL2 + ((size_t)g*2 + (1-s))*2048;
  unsigned long long* recIC_mine  = recIC + ((size_t)g*2 + s)*2048;
  unsigned long long* recIC_other = recIC + ((size_t)g*2 + (1-s))*2048;

  // remote-fill decode for lane index tid (matches producer packing)
  const int rq   = lane >> 4;
  const int r_m0 = (rq & 1)*4 + (rq >> 1)*2;
  const int r_u  = w*16 + c;                   // remote-local unit 0..127
  const int rk   = (1-s)*128 + r_u;            // K-column in LDS

  const __hip_bfloat16* gxg = gx + ((((size_t)g*Tn)*2 + s)*8 + w)*4*128;

  // prologue gx prefetch for t=0
  ushort4 gxr[4];
  if (quad < 2){
    const __hip_bfloat16* gp0 = gxg + c*8 + quad*4;
#pragma unroll
    for (int G=0; G<4; G++) gxr[G] = *(const ushort4*)(gp0 + G*128);
  }

  bool fastok = true;
  int  misses = 0;

  for (int t=0; t<Tn; t++){
    const int buf  = (t & 1) * 8*272;
    const int nbuf = ((t+1) & 1) * 8*272;

    // ---- acc init from gx (hi rows) ----
    f32x4 acc[4];
#pragma unroll
    for (int G=0; G<4; G++){
      if (quad < 2){
        acc[G][0]=bf2f(gxr[G].x); acc[G][1]=bf2f(gxr[G].y);
        acc[G][2]=bf2f(gxr[G].z); acc[G][3]=bf2f(gxr[G].w);
      } else {
        acc[G][0]=0.f; acc[G][1]=0.f; acc[G][2]=0.f; acc[G][3]=0.f;
      }
    }

    // ---- h MFMA on [buf] (filled completely at the end of step t-1) ----
    if (t > 0){
      const unsigned short* hb = (c < 8) ? &hhi[buf + c*272] : &hlo[buf + (c-8)*272];
#pragma unroll
      for (int kb=0; kb<8; kb++){
        const s16x8 af = *(const s16x8*)(hb + kb*32 + quad*8);
        acc[0] = __builtin_amdgcn_mfma_f32_16x16x32_bf16(af, whh[0][kb], acc[0],0,0,0);
        acc[1] = __builtin_amdgcn_mfma_f32_16x16x32_bf16(af, whh[1][kb], acc[1],0,0,0);
        acc[2] = __builtin_amdgcn_mfma_f32_16x16x32_bf16(af, whh[2][kb], acc[2],0,0,0);
        acc[3] = __builtin_amdgcn_mfma_f32_16x16x32_bf16(af, whh[3][kb], acc[3],0,0,0);
      }
    }

    // ---- epilogue: combine hi/lo via shfl_xor(32); 2 LSTM updates/lane ----
    float hv[2];
#pragma unroll
    for (int rp=0; rp<2; rp++){
      const int rr  = rsel0 + rp;
      const int prr = prr0 + rp;
      const float gi = acc[0][rr] + __shfl_xor(acc[0][prr], 32);
      const float gf = acc[1][rr] + __shfl_xor(acc[1][prr], 32);
      const float gg = acc[2][rr] + __shfl_xor(acc[2][prr], 32);
      const float go = acc[3][rr] + __shfl_xor(acc[3][prr], 32);
      const float cn = sigf(gf)*cst[rp] + sigf(gi)*tanh_fast(gg);
      cst[rp] = cn;
      hv[rp] = sigf(go)*tanh_fast(cn);
    }

    // ---- pack hi/lo; dual-publish tagged record ----
    unsigned short hi[2], lo[2];
    hi[0] = f2bf_rn(hv[0]); lo[0] = f2bf_rn(hv[0] - bf2f(hi[0]));
    hi[1] = f2bf_rn(hv[1]); lo[1] = f2bf_rn(hv[1] - bf2f(hi[1]));
    if (t < Tn-1){
      const unsigned tg16 = ((unsigned)(t+1)) << 16;
      u32x4 r;
      r[0] = (unsigned)hi[0] | tg16; r[1] = (unsigned)hi[1] | tg16;
      r[2] = (unsigned)lo[0] | tg16; r[3] = (unsigned)lo[1] | tg16;
      st_b128_l2(recL2_mine + (size_t)(t & 1)*1024 + 2*tid, r);
      const unsigned long long w0 =
          (unsigned long long)r[0] | ((unsigned long long)r[1] << 32);
      const unsigned long long w1 =
          (unsigned long long)r[2] | ((unsigned long long)r[3] << 32);
      unsigned long long* rmIC = recIC_mine + (size_t)(t & 1)*1024 + 2*tid;
      __hip_atomic_store(rmIC,   w0, __ATOMIC_RELAXED, __HIP_MEMORY_SCOPE_AGENT);
      __hip_atomic_store(rmIC+1, w1, __ATOMIC_RELAXED, __HIP_MEMORY_SCOPE_AGENT);
    }

    // ---- own half of next step's LDS + encode output ----
#pragma unroll
    for (int rp=0; rp<2; rp++){
      const int m = m0 + rp;
      hhi[nbuf + m*272 + u] = hi[rp];
      hlo[nbuf + m*272 + u] = lo[rp];
      out[enc_base + ((size_t)(b0+m)*Tn + t)*Hn + u] = hv[rp];
    }

    // ---- gx prefetch for t+1 (off the serial path) ----
    if (t+1 < Tn && quad < 2){
      const __hip_bfloat16* gp = gxg + (size_t)(t+1)*2*8*4*128 + c*8 + quad*4;
#pragma unroll
      for (int G=0; G<4; G++) gxr[G] = *(const ushort4*)(gp + G*128);
    }

    // ---- receive partner's record; fill remote half of NEXT buffer ----
    if (t < Tn-1){
      const unsigned tg = (unsigned)(t+1);
      const unsigned long long* roL2 = recL2_other + (size_t)(t & 1)*1024 + 2*tid;
      const unsigned long long* roIC = recIC_other + (size_t)(t & 1)*1024 + 2*tid;
      unsigned short vh0, vh1, vl0, vl1;
      bool got = false;
      if (fastok){
        const int nspin = (t == 0) ? 4000 : 64;   // t=0 generous for launch skew
        for (int sp=0; sp<nspin; ++sp){
          u32x4 r = ld_b128_sc0(roL2);
          if ((r[0]>>16)==tg && (r[1]>>16)==tg && (r[2]>>16)==tg && (r[3]>>16)==tg){
            vh0=(unsigned short)r[0]; vh1=(unsigned short)r[1];
            vl0=(unsigned short)r[2]; vl1=(unsigned short)r[3];
            got = true; break;
          }
        }
        if (!got){ if (++misses >= 2) fastok = false; }
        else misses = 0;
      }
      if (!got){
        for (;;){
          const unsigned long long w0 =
            __hip_atomic_load(roIC,   __ATOMIC_RELAXED, __HIP_MEMORY_SCOPE_AGENT);
          const unsigned long long w1 =
            __hip_atomic_load(roIC+1, __ATOMIC_RELAXED, __HIP_MEMORY_SCOPE_AGENT);
          if (((w0 >> 16) & 0xffffu) == tg && (w0 >> 48) == tg &&
              ((w1 >> 16) & 0xffffu) == tg && (w1 >> 48) == tg){
            vh0=(unsigned short)w0; vh1=(unsigned short)(w0 >> 32);
            vl0=(unsigned short)w1; vl1=(unsigned short)(w1 >> 32);
            break;
          }
          __builtin_amdgcn_s_sleep(1);
        }
      }
      hhi[nbuf + r_m0*272 + rk]     = vh0;
      hhi[nbuf + (r_m0+1)*272 + rk] = vh1;
      hlo[nbuf + r_m0*272 + rk]     = vl0;
      hlo[nbuf + (r_m0+1)*272 + rk] = vl1;
    }

    __syncthreads();
  }
}

extern "C" void kernel_launch(void* const* d_in, const int* in_sizes, int n_in,
                              void* d_out, int out_size, void* d_ws, size_t ws_size,
                              hipStream_t stream) {
  const float* input = (const float*)d_in[0];
  const float* W_ih  = (const float*)d_in[1];
  const float* W_hh  = (const float*)d_in[2];
  const float* b_ih  = (const float*)d_in[3];
  const float* b_hh  = (const float*)d_in[4];
  const float* fc_w  = (const float*)d_in[5];
  float* out = (float*)d_out;

  char* wsb = (char*)d_ws;
  __hip_bfloat16* gxp = (__hip_bfloat16*)wsb;
  unsigned long long* recL2 = (unsigned long long*)(wsb + RECL2_OFF);
  // IC backstop gets its own buffer when the workspace has room; otherwise
  // alias (degrades to the dual-store-same-address protocol, still correct
  // in the expected same-XCD case).
  const bool dual = (ws_size >= RECIC_OFF + REC_BYTES);
  unsigned long long* recIC = dual ? (unsigned long long*)(wsb + RECIC_OFF) : recL2;

  hipMemsetAsync(recL2, 0, dual ? 2*REC_BYTES : REC_BYTES, stream);
  phase0_kernel<<<Bn, 256, 0, stream>>>(input, fc_w, out);
  gx_kernel<<<512, 256, 0, stream>>>(out, W_ih, b_ih, b_hh, gxp);
  scan_kernel<<<64, 512, 0, stream>>>(W_hh, out, gxp, recL2, recIC);
}

// Round 6
// 554.705 us; speedup vs baseline: 2.6962x; 2.6962x over previous
//
#include <hip/hip_runtime.h>
#include <hip/hip_bf16.h>
#include <stdint.h>

#define Bn 256
#define Tn 127
#define Kn 128
#define Hn 256

typedef float f32x4 __attribute__((ext_vector_type(4)));
typedef short s16x8 __attribute__((ext_vector_type(8)));
typedef unsigned int u32x4 __attribute__((ext_vector_type(4)));

// ws layout
#define GX_BYTES   66584576ULL   // bf16 [32][127][2][8][4][128]
#define RECL2_OFF  66584576ULL   // L2-path tagged records (1MB)
#define REC_BYTES  1048576ULL
#define RECIC_OFF  (RECL2_OFF + REC_BYTES)   // IC-path tagged records (1MB)
#define META_OFF   (RECIC_OFF + REC_BYTES)   // xcc_of[64] + pad
#define META_BYTES 4096ULL
#define WIH_OFF    (META_OFF + META_BYTES)   // bf16 W_ih, 256KB
#define WHH_OFF    (WIH_OFF + 262144ULL)     // bf16 W_hh, 512KB
#define WS_FULL    (WHH_OFF + 524288ULL)

__device__ __forceinline__ float bf2f(unsigned short b){
  union { unsigned u; float f; } v; v.u = ((unsigned)b) << 16; return v.f;
}
__device__ __forceinline__ unsigned short f2bf_rn(float f){
  union { __hip_bfloat16 h; unsigned short s; } u;
  u.h = __float2bfloat16(f);
  return u.s;
}
__device__ __forceinline__ s16x8 cvt8(f32x4 a, f32x4 b){
  union { __hip_bfloat162 h2; unsigned short s[2]; } u0,u1,u2,u3;
  u0.h2 = __float22bfloat162_rn(float2{a[0],a[1]});
  u1.h2 = __float22bfloat162_rn(float2{a[2],a[3]});
  u2.h2 = __float22bfloat162_rn(float2{b[0],b[1]});
  u3.h2 = __float22bfloat162_rn(float2{b[2],b[3]});
  s16x8 r;
  r[0]=(short)u0.s[0]; r[1]=(short)u0.s[1]; r[2]=(short)u1.s[0]; r[3]=(short)u1.s[1];
  r[4]=(short)u2.s[0]; r[5]=(short)u2.s[1]; r[6]=(short)u3.s[0]; r[7]=(short)u3.s[1];
  return r;
}
__device__ __forceinline__ float sigf(float x){ return 1.f/(1.f+__expf(-x)); }
__device__ __forceinline__ float tanh_fast(float x){
  float ax = fabsf(x);
  float e = __expf(-2.f*ax);
  float t = (1.f - e)/(1.f + e);
  return x < 0.f ? -t : t;
}

// L2-visible 16B load (sc0 = bypass L1, served by this XCD's L2)
__device__ __forceinline__ u32x4 ld_b128_sc0(const void* p){
  u32x4 r;
  asm volatile("global_load_dwordx4 %0, %1, off sc0\n\ts_waitcnt vmcnt(0)"
               : "=v"(r) : "v"(p) : "memory");
  return r;
}
// plain 16B store (lands in producer XCD's L2)
__device__ __forceinline__ void st_b128_l2(void* p, u32x4 v){
  asm volatile("global_store_dwordx4 %0, %1, off" :: "v"(p), "v"(v) : "memory");
}

// ---------------- W conversion: f32 -> bf16, once per launch ----------------
__global__ __launch_bounds__(256) void wconv_kernel(
    const float* __restrict__ Wih, const float* __restrict__ Whh,
    __hip_bfloat16* __restrict__ Bih, __hip_bfloat16* __restrict__ Bhh)
{
  const int i = blockIdx.x*256 + threadIdx.x;   // grid 192*256 = 49152
  const float* src; __hip_bfloat16* dst; int j;
  if (i < 16384){ src = Wih; dst = Bih; j = i; }          // 131072 f32
  else          { src = Whh; dst = Bhh; j = i - 16384; }  // 262144 f32
  const f32x4 a = *(const f32x4*)(src + (size_t)j*8);
  const f32x4 b = *(const f32x4*)(src + (size_t)j*8 + 4);
  s16x8 r = cvt8(a, b);
  *(s16x8*)(dst + (size_t)j*8) = r;
}

// ---------------- Phase 0: alpha = softmax(x_score), weight = alpha*input -----
__global__ __launch_bounds__(256) void phase0_kernel(
    const float* __restrict__ in, const float* __restrict__ fc_w,
    float* __restrict__ out)
{
  const int b    = blockIdx.x;
  const int tid  = threadIdx.x;
  const int k    = tid & 127;
  const int half = tid >> 7;
  __shared__ float wx[Tn+1];
  __shared__ float partial[2][128];
  __shared__ float red[8];
  __shared__ float alpha_s[128];
  if (tid < Tn) wx[tid] = fc_w[2*Hn + tid];
  __syncthreads();

  const float* ib = in + (size_t)b*Tn*Kn;
  const int t0 = half*64, t1 = half ? Tn : 64;
  float acc = 0.f;
  for (int t=t0; t<t1; t++) acc += ib[t*Kn + k] * wx[t];
  partial[half][k] = acc;
  __syncthreads();
  const float tot = partial[0][k] + partial[1][k];

  float mx = tot;
#pragma unroll
  for (int o=32;o>0;o>>=1) mx = fmaxf(mx, __shfl_xor(mx, o));
  const int wv = tid >> 6;
  if ((tid & 63) == 0) red[wv] = mx;
  __syncthreads();
  mx = fmaxf(fmaxf(red[0],red[1]), fmaxf(red[2],red[3]));
  float e = __expf(tot - mx);
  float sm = e;
#pragma unroll
  for (int o=32;o>0;o>>=1) sm += __shfl_xor(sm, o);
  if ((tid & 63) == 0) red[4+wv] = sm;
  __syncthreads();
  if (half == 0) alpha_s[k] = e / (red[4] + red[5]);
  __syncthreads();

  const int k4 = tid & 31;
  const int tr = tid >> 5;
  const f32x4 al4 = *(const f32x4*)&alpha_s[k4*4];
  float* ob = out + (size_t)b*Tn*Kn;
  for (int t=tr; t<Tn; t+=8){
    f32x4 v = *(const f32x4*)(ib + t*Kn + k4*4);
    v[0]*=al4[0]; v[1]*=al4[1]; v[2]*=al4[2]; v[3]*=al4[3];
    *(f32x4*)(ob + t*Kn + k4*4) = v;
  }
}

// ---------------- Phase GX: gx = x @ W_ih^T + bias, packed in MFMA C-layout --
__global__ __launch_bounds__(256) void gx_kernel(
    const float* __restrict__ xw, const float* __restrict__ W_ih,
    const __hip_bfloat16* __restrict__ Bih,
    const float* __restrict__ b_ih, const float* __restrict__ b_hh,
    __hip_bfloat16* __restrict__ gx, int pre)
{
  const int g    = blockIdx.x & 31;
  const int tpb  = blockIdx.x >> 5;       // 0..15
  const int tid  = threadIdx.x;
  const int wv   = tid >> 6;
  const int lane = tid & 63;
  const int c    = lane & 15;
  const int quad = lane >> 4;

  const int b  = g*8 + (c & 7);

  s16x8 afr[4][4];
#pragma unroll
  for (int tpi=0; tpi<4; tpi++){
    const int t0 = (tpb*4 + tpi)*2;
    const int tt = min(t0 + (c >> 3), Tn-1);
    const float* xp = xw + ((size_t)b*Tn + tt)*Kn + quad*8;
#pragma unroll
    for (int kb=0; kb<4; kb++)
      afr[tpi][kb] = cvt8(*(const f32x4*)(xp + kb*32), *(const f32x4*)(xp + kb*32 + 4));
  }

  const int tof = (quad >> 1);
  const int mh  = (quad & 1) * 4;

  for (int j = wv*16; j < wv*16+16; j++){
    const int n = j*16 + c;
    const float bias = b_ih[n] + b_hh[n];
    s16x8 bfr[4];
    if (pre){
      const __hip_bfloat16* wp = Bih + (size_t)n*Kn + quad*8;
#pragma unroll
      for (int kb=0; kb<4; kb++) bfr[kb] = *(const s16x8*)(wp + kb*32);
    } else {
      const float* wp = W_ih + (size_t)n*Kn + quad*8;
#pragma unroll
      for (int kb=0; kb<4; kb++)
        bfr[kb] = cvt8(*(const f32x4*)(wp + kb*32), *(const f32x4*)(wp + kb*32 + 4));
    }
    const int G = j >> 4, rem = j & 15, s = rem >> 3, w8 = rem & 7;
#pragma unroll
    for (int tpi=0; tpi<4; tpi++){
      f32x4 acc = {bias, bias, bias, bias};
#pragma unroll
      for (int kb=0; kb<4; kb++)
        acc = __builtin_amdgcn_mfma_f32_16x16x32_bf16(afr[tpi][kb], bfr[kb], acc, 0,0,0);
      const int trow = (tpb*4 + tpi)*2 + tof;
      if (trow < Tn){
        __hip_bfloat16* dst = gx +
          (((((size_t)g*Tn + trow)*2 + s)*8 + w8)*4 + G)*128 + c*8 + mh;
        ushort4 pk;
        pk.x = f2bf_rn(acc[0]); pk.y = f2bf_rn(acc[1]);
        pk.z = f2bf_rn(acc[2]); pk.w = f2bf_rn(acc[3]);
        *(ushort4*)dst = pk;
      }
    }
  }
}

// ---------------- Scan: 32 groups x 2 N-slices, W_hh-only in registers ------
// Dynamic pairing by measured XCC_ID (deterministic, globally consistent);
// same-XCD pairs try the shared-L2 exchange (bounded 10-probe, 3-strike
// latch); everything else uses the proven IC protocol. Producer always
// dual-publishes so no path can hang.
__global__ __launch_bounds__(512, 2) void scan_kernel(
    const float* __restrict__ W_hh, const __hip_bfloat16* __restrict__ Bhh,
    float* __restrict__ out, const __hip_bfloat16* __restrict__ gx,
    unsigned long long* __restrict__ recL2, unsigned long long* __restrict__ recIC,
    unsigned* __restrict__ meta, int mode)
{
  const int bid  = blockIdx.x;
  const int tid  = threadIdx.x;
  const int w    = tid >> 6;          // wave 0..7 (unit-group)
  const int lane = tid & 63;
  const int c    = lane & 15;
  const int quad = lane >> 4;

  __shared__ __align__(16) unsigned short hhi[2*8*272];
  __shared__ __align__(16) unsigned short hlo[2*8*272];
  __shared__ unsigned short xv_sh[64];
  __shared__ int pair_sh[3];

  int g, s, same;
  if (mode){
    // ---- publish my XCC, gather all 64, deterministic pairing ----
    if (tid == 0){
      unsigned xcc;
      asm volatile("s_getreg_b32 %0, hwreg(HW_REG_XCC_ID)" : "=s"(xcc));
      __hip_atomic_store(&meta[bid], (xcc & 7) + 1,
                         __ATOMIC_RELAXED, __HIP_MEMORY_SCOPE_AGENT);
    }
    if (tid < 64){
      unsigned v;
      while ((v = __hip_atomic_load(&meta[tid], __ATOMIC_RELAXED,
                                    __HIP_MEMORY_SCOPE_AGENT)) == 0u)
        __builtin_amdgcn_s_sleep(2);
      xv_sh[tid] = (unsigned short)(v - 1);
    }
    __syncthreads();
    if (tid == 0){
      unsigned long long pend = 0;  // per-xcd: (bid+1) of unpaired block
      int myg = -1, mys = 0, sm = 0, pcnt = 0;
      for (int i=0; i<64; i++){
        const int x  = xv_sh[i];
        const int pb = (int)((pend >> (8*x)) & 0xffULL);
        if (pb){
          if (i == bid)    { myg = pcnt; mys = 1; sm = 1; }
          if (pb-1 == bid) { myg = pcnt; mys = 0; sm = 1; }
          pcnt++;
          pend &= ~(0xffULL << (8*x));
        } else {
          pend |= ((unsigned long long)(i+1)) << (8*x);
        }
      }
      int prev = -1;
      for (int i=0; i<64; i++){
        const int x = xv_sh[i];
        if ((int)((pend >> (8*x)) & 0xffULL) == i+1){
          if (prev < 0) prev = i;
          else {
            if (i == bid)    { myg = pcnt; mys = 1; }
            if (prev == bid) { myg = pcnt; mys = 0; }
            pcnt++; prev = -1;
          }
        }
      }
      pair_sh[0] = myg; pair_sh[1] = mys; pair_sh[2] = sm;
    }
    __syncthreads();
    g = pair_sh[0]; s = pair_sh[1]; same = pair_sh[2];
  } else {
    s = (bid >> 3) & 1;
    g = (bid & 7) | ((bid >> 4) << 3);
    same = 0;
  }

  const int b0 = g * 8;
  const int u  = s*128 + w*16 + c;    // global hidden unit

  // persistent W_hh B-frags: 4 gates x 8 kb = 128 regs
  s16x8 whh[4][8];
  if (mode){
#pragma unroll
    for (int G=0; G<4; G++){
      const __hip_bfloat16* p0 = Bhh + (size_t)(G*Hn + u)*Hn + quad*8;
#pragma unroll
      for (int kb=0; kb<8; kb++) whh[G][kb] = *(const s16x8*)(p0 + kb*32);
    }
  } else {
#pragma unroll
    for (int G=0; G<4; G++){
      const float* p0 = W_hh + (size_t)(G*Hn + u)*Hn + quad*8;
#pragma unroll
      for (int kb=0; kb<8; kb++)
        whh[G][kb] = cvt8(*(const f32x4*)(p0 + kb*32), *(const f32x4*)(p0 + kb*32 + 4));
    }
  }

  const int rsel0 = (quad >> 1) * 2;
  const int prr0  = rsel0 ^ 2;
  const int m0    = (quad & 1)*4 + rsel0;
  float cst[2] = {0.f, 0.f};

  const size_t enc_base = (size_t)Bn*Tn*Kn;
  unsigned long long* recL2_mine  = recL2 + ((size_t)g*2 + s)*2048;
  unsigned long long* recL2_other = recL2 + ((size_t)g*2 + (1-s))*2048;
  unsigned long long* recIC_mine  = recIC + ((size_t)g*2 + s)*2048;
  unsigned long long* recIC_other = recIC + ((size_t)g*2 + (1-s))*2048;

  // remote-fill decode for lane index tid (matches producer packing)
  const int rq   = lane >> 4;
  const int r_m0 = (rq & 1)*4 + (rq >> 1)*2;
  const int r_u  = w*16 + c;                   // remote-local unit 0..127
  const int rk   = (1-s)*128 + r_u;            // K-column in LDS

  const __hip_bfloat16* gxg = gx + ((((size_t)g*Tn)*2 + s)*8 + w)*4*128;

  // prologue gx prefetch for t=0
  ushort4 gxr[4];
  if (quad < 2){
    const __hip_bfloat16* gp0 = gxg + c*8 + quad*4;
#pragma unroll
    for (int G=0; G<4; G++) gxr[G] = *(const ushort4*)(gp0 + G*128);
  }

  int strikes = 0;   // per-thread fast-path failure count; >=3 -> IC only

  for (int t=0; t<Tn; t++){
    const int buf  = (t & 1) * 8*272;
    const int nbuf = ((t+1) & 1) * 8*272;

    // ---- acc init from gx (hi rows) ----
    f32x4 acc[4];
#pragma unroll
    for (int G=0; G<4; G++){
      if (quad < 2){
        acc[G][0]=bf2f(gxr[G].x); acc[G][1]=bf2f(gxr[G].y);
        acc[G][2]=bf2f(gxr[G].z); acc[G][3]=bf2f(gxr[G].w);
      } else {
        acc[G][0]=0.f; acc[G][1]=0.f; acc[G][2]=0.f; acc[G][3]=0.f;
      }
    }

    // ---- h MFMA on [buf] (filled completely at the end of step t-1) ----
    if (t > 0){
      const unsigned short* hb = (c < 8) ? &hhi[buf + c*272] : &hlo[buf + (c-8)*272];
#pragma unroll
      for (int kb=0; kb<8; kb++){
        const s16x8 af = *(const s16x8*)(hb + kb*32 + quad*8);
        acc[0] = __builtin_amdgcn_mfma_f32_16x16x32_bf16(af, whh[0][kb], acc[0],0,0,0);
        acc[1] = __builtin_amdgcn_mfma_f32_16x16x32_bf16(af, whh[1][kb], acc[1],0,0,0);
        acc[2] = __builtin_amdgcn_mfma_f32_16x16x32_bf16(af, whh[2][kb], acc[2],0,0,0);
        acc[3] = __builtin_amdgcn_mfma_f32_16x16x32_bf16(af, whh[3][kb], acc[3],0,0,0);
      }
    }

    // ---- epilogue: combine hi/lo via shfl_xor(32); 2 LSTM updates/lane ----
    float hv[2];
#pragma unroll
    for (int rp=0; rp<2; rp++){
      const int rr  = rsel0 + rp;
      const int prr = prr0 + rp;
      const float gi = acc[0][rr] + __shfl_xor(acc[0][prr], 32);
      const float gf = acc[1][rr] + __shfl_xor(acc[1][prr], 32);
      const float gg = acc[2][rr] + __shfl_xor(acc[2][prr], 32);
      const float go = acc[3][rr] + __shfl_xor(acc[3][prr], 32);
      const float cn = sigf(gf)*cst[rp] + sigf(gi)*tanh_fast(gg);
      cst[rp] = cn;
      hv[rp] = sigf(go)*tanh_fast(cn);
    }

    // ---- pack hi/lo; dual-publish tagged record ----
    unsigned short hi[2], lo[2];
    hi[0] = f2bf_rn(hv[0]); lo[0] = f2bf_rn(hv[0] - bf2f(hi[0]));
    hi[1] = f2bf_rn(hv[1]); lo[1] = f2bf_rn(hv[1] - bf2f(hi[1]));
    if (t < Tn-1){
      const unsigned tg16 = ((unsigned)(t+1)) << 16;
      u32x4 r;
      r[0] = (unsigned)hi[0] | tg16; r[1] = (unsigned)hi[1] | tg16;
      r[2] = (unsigned)lo[0] | tg16; r[3] = (unsigned)lo[1] | tg16;
      if (mode)  // separate L2 buffer only exists in full mode (no aliasing)
        st_b128_l2(recL2_mine + (size_t)(t & 1)*1024 + 2*tid, r);
      const unsigned long long w0 =
          (unsigned long long)r[0] | ((unsigned long long)r[1] << 32);
      const unsigned long long w1 =
          (unsigned long long)r[2] | ((unsigned long long)r[3] << 32);
      unsigned long long* rmIC = recIC_mine + (size_t)(t & 1)*1024 + 2*tid;
      __hip_atomic_store(rmIC,   w0, __ATOMIC_RELAXED, __HIP_MEMORY_SCOPE_AGENT);
      __hip_atomic_store(rmIC+1, w1, __ATOMIC_RELAXED, __HIP_MEMORY_SCOPE_AGENT);
    }

    // ---- own half of next step's LDS + encode output ----
#pragma unroll
    for (int rp=0; rp<2; rp++){
      const int m = m0 + rp;
      hhi[nbuf + m*272 + u] = hi[rp];
      hlo[nbuf + m*272 + u] = lo[rp];
      out[enc_base + ((size_t)(b0+m)*Tn + t)*Hn + u] = hv[rp];
    }

    // ---- gx prefetch for t+1 (off the serial path) ----
    if (t+1 < Tn && quad < 2){
      const __hip_bfloat16* gp = gxg + (size_t)(t+1)*2*8*4*128 + c*8 + quad*4;
#pragma unroll
      for (int G=0; G<4; G++) gxr[G] = *(const ushort4*)(gp + G*128);
    }

    // ---- receive partner's record; fill remote half of NEXT buffer ----
    if (t < Tn-1){
      const unsigned tg = (unsigned)(t+1);
      unsigned short vh0, vh1, vl0, vl1;
      bool got = false;
      if (same && t > 0 && strikes < 3){
        // bounded 10-probe L2 attempt, then give up for this step
        const unsigned long long* roL2 = recL2_other + (size_t)(t & 1)*1024 + 2*tid;
        for (int sp=0; sp<10; ++sp){
          u32x4 r = ld_b128_sc0(roL2);
          if ((r[0]>>16)==tg && (r[1]>>16)==tg && (r[2]>>16)==tg && (r[3]>>16)==tg){
            vh0=(unsigned short)r[0]; vh1=(unsigned short)r[1];
            vl0=(unsigned short)r[2]; vl1=(unsigned short)r[3];
            got = true; break;
          }
        }
        strikes = got ? 0 : (strikes + 1);
      }
      if (!got){
        const unsigned long long* roIC = recIC_other + (size_t)(t & 1)*1024 + 2*tid;
        for (;;){
          const unsigned long long w0 =
            __hip_atomic_load(roIC,   __ATOMIC_RELAXED, __HIP_MEMORY_SCOPE_AGENT);
          const unsigned long long w1 =
            __hip_atomic_load(roIC+1, __ATOMIC_RELAXED, __HIP_MEMORY_SCOPE_AGENT);
          if (((w0 >> 16) & 0xffffu) == tg && (w0 >> 48) == tg &&
              ((w1 >> 16) & 0xffffu) == tg && (w1 >> 48) == tg){
            vh0=(unsigned short)w0; vh1=(unsigned short)(w0 >> 32);
            vl0=(unsigned short)w1; vl1=(unsigned short)(w1 >> 32);
            break;
          }
          __builtin_amdgcn_s_sleep(1);
        }
      }
      hhi[nbuf + r_m0*272 + rk]     = vh0;
      hhi[nbuf + (r_m0+1)*272 + rk] = vh1;
      hlo[nbuf + r_m0*272 + rk]     = vl0;
      hlo[nbuf + (r_m0+1)*272 + rk] = vl1;
    }

    __syncthreads();
  }
}

extern "C" void kernel_launch(void* const* d_in, const int* in_sizes, int n_in,
                              void* d_out, int out_size, void* d_ws, size_t ws_size,
                              hipStream_t stream) {
  const float* input = (const float*)d_in[0];
  const float* W_ih  = (const float*)d_in[1];
  const float* W_hh  = (const float*)d_in[2];
  const float* b_ih  = (const float*)d_in[3];
  const float* b_hh  = (const float*)d_in[4];
  const float* fc_w  = (const float*)d_in[5];
  float* out = (float*)d_out;

  char* wsb = (char*)d_ws;
  __hip_bfloat16* gxp = (__hip_bfloat16*)wsb;

  const int full = (ws_size >= WS_FULL) ? 1 : 0;
  unsigned long long* recL2 = (unsigned long long*)(wsb + RECL2_OFF);
  unsigned long long* recIC = full ? (unsigned long long*)(wsb + RECIC_OFF) : recL2;
  unsigned* meta            = full ? (unsigned*)(wsb + META_OFF) : (unsigned*)recL2;
  __hip_bfloat16* Bih       = full ? (__hip_bfloat16*)(wsb + WIH_OFF) : (__hip_bfloat16*)recL2;
  __hip_bfloat16* Bhh       = full ? (__hip_bfloat16*)(wsb + WHH_OFF) : (__hip_bfloat16*)recL2;

  hipMemsetAsync(recL2, 0, full ? (2*REC_BYTES + META_BYTES) : REC_BYTES, stream);
  if (full)
    wconv_kernel<<<192, 256, 0, stream>>>(W_ih, W_hh, Bih, Bhh);
  phase0_kernel<<<Bn, 256, 0, stream>>>(input, fc_w, out);
  gx_kernel<<<512, 256, 0, stream>>>(out, W_ih, Bih, b_ih, b_hh, gxp, full);
  scan_kernel<<<64, 512, 0, stream>>>(W_hh, Bhh, out, gxp, recL2, recIC, meta, full);
}